// Round 15
// baseline (6919.441 us; speedup 1.0000x reference)
//
#include <hip/hip_runtime.h>
#include <cmath>

#define S_CNT 50
#define T_CNT 2048
#define I_DIM 64
#define H_DIM 256
#define CHK   8            // timesteps per u-register chunk
#define NCHK  (T_CNT / CHK)

typedef float vf2 __attribute__((ext_vector_type(2)));

__device__ __forceinline__ float fast_tanh(float x) {
    float e = __expf(2.0f * x);
    return 1.0f - __fdividef(2.0f, e + 1.0f);
}

__device__ __forceinline__ vf2 pkfma(vf2 a, vf2 b, vf2 c) {
#if __has_builtin(__builtin_elementwise_fma)
    return __builtin_elementwise_fma(a, b, c);
#else
    vf2 r; r.x = fmaf(a.x, b.x, c.x); r.y = fmaf(a.y, b.y, c.y); return r;
#endif
}

__device__ __forceinline__ float fma4(const float4 w, const float4 h, float a) {
    a = fmaf(w.x, h.x, a);
    a = fmaf(w.y, h.y, a);
    a = fmaf(w.z, h.z, a);
    a = fmaf(w.w, h.w, a);
    return a;
}

// x + DPP(x): VALU-pipe cross-lane add. CTRLs: 0xB1 quad xor1, 0x4E quad
// xor2, 0x141 row_half_mirror (lane^7 within each 8-lane half-row).
template <int CTRL>
__device__ __forceinline__ float dpp_xadd(float x) {
    const int xi = __float_as_int(x);
    const int yi = __builtin_amdgcn_update_dpp(xi, xi, CTRL, 0xF, 0xF, false);
    return x + __int_as_float(yi);
}

// Barrier that drains ONLY LDS (lgkmcnt), leaving global loads/stores in
// flight (vmcnt never drained in-loop). Verified race-free r10/r12.
__device__ __forceinline__ void lds_barrier() {
    __builtin_amdgcn_sched_barrier(0);
    asm volatile("s_waitcnt lgkmcnt(0)");
    __builtin_amdgcn_s_barrier();
    __builtin_amdgcn_sched_barrier(0);
}

// Fully fused: u on-the-fly (half-dot per dup-pair lane, merged by DPP at
// consumption), r12 recurrence core (8 waves, all-DPP reduce, lgkm-only
// barrier), sigma/log-lik epilogue. One kernel, one launch.
__global__
__launch_bounds__(512)
__attribute__((amdgpu_waves_per_eu(1, 2)))
void rnn_fused(const float* __restrict__ input_data,
               const float* __restrict__ hidden,
               const float* __restrict__ fe,
               const float* __restrict__ W_ih,
               const float* __restrict__ W_hh,
               const float* __restrict__ b_ih,
               const float* __restrict__ b_hh,
               const float* __restrict__ W_lin,
               const float* __restrict__ b_lin,
               float* __restrict__ Hall,   // workspace: h trace [S][T][H]
               float* __restrict__ out)
{
    const int s   = blockIdx.x;
    const int tid = threadIdx.x;
    const int g   = tid >> 3;    // 0..63: row group (rows 4g..4g+3)
    const int p   = tid & 7;     // col slice

    const int s1 = (p ^ (p >> 2)) & 1;
    const int s2 = (p ^ (p >> 1)) & 1;
    const int jown = 4 * g + s1 + 2 * s2;
    const int xh  = (p >> 2) * 32;   // x-half offset for this lane's u-dot

    __shared__ __align__(16) float hA[H_DIM];
    __shared__ __align__(16) float hB[H_DIM];
    __shared__ __align__(16) float xbuf[2][CHK][I_DIM];  // x staging ring
    __shared__ float red[8];

    const float* inb = input_data + (size_t)s * T_CNT * 65;

    if (tid < H_DIM) hA[tid] = hidden[s * H_DIM + tid];

    // W_hh weights: 4 rows x 8 chunks of float4 (f = 8m+p), packed vf2 (r12)
    vf2 w2[4][16];
#pragma unroll
    for (int r = 0; r < 4; ++r) {
        const float4* wrow = reinterpret_cast<const float4*>(
            W_hh + ((size_t)s * H_DIM + 4 * g + r) * H_DIM);
#pragma unroll
        for (int m = 0; m < 8; ++m) {
            const float4 wv = wrow[8 * m + p];
            w2[r][2 * m]     = vf2{wv.x, wv.y};
            w2[r][2 * m + 1] = vf2{wv.z, wv.w};
        }
    }

    // W_ih half-row for jown (dup-pair lanes p and p^7 take opposite halves)
    vf2 wih[16];
    {
        const float4* wr = reinterpret_cast<const float4*>(
            W_ih + ((size_t)s * H_DIM + jown) * I_DIM + xh);
#pragma unroll
        for (int m = 0; m < 8; ++m) {
            const float4 v = wr[m];
            wih[2 * m]     = vf2{v.x, v.y};
            wih[2 * m + 1] = vf2{v.z, v.w};
        }
    }
    const float badd = b_ih[s * H_DIM + jown] + b_hh[s * H_DIM + jown];

    // stage x chunks 0,1 into LDS; register pipeline holds chunks 2,3
    {
        const int r = tid >> 6, col = tid & 63;
        xbuf[0][r][col] = inb[(size_t)r * 65 + 1 + col];
        xbuf[1][r][col] = inb[(size_t)(CHK + r) * 65 + 1 + col];
    }
    float xreg_cur = inb[(size_t)(2 * CHK + (tid >> 6)) * 65 + 1 + (tid & 63)];
    float xreg_nxt = inb[(size_t)(3 * CHK + (tid >> 6)) * 65 + 1 + (tid & 63)];

    float* Hb = Hall + (size_t)s * T_CNT * H_DIM;
    float* us = Hb + jown;           // h store ptr (advances H_DIM/step)

    const bool wsel = (p < 4);
    const bool sel1 = (s1 != 0);
    const bool sel2 = (s2 != 0);

    __syncthreads();

    // u half-dots for chunk 0 (from xbuf[0])
#define UHALF(DST, XPTR)                                                      \
    {                                                                         \
        const float4* uxk = reinterpret_cast<const float4*>(XPTR);            \
        const float4 q0 = uxk[0], q1 = uxk[1], q2 = uxk[2], q3 = uxk[3];      \
        const float4 q4 = uxk[4], q5 = uxk[5], q6 = uxk[6], q7 = uxk[7];      \
        vf2 uu0 = vf2{0.f, 0.f}, uu1 = vf2{0.f, 0.f};                         \
        vf2 uu2 = vf2{0.f, 0.f}, uu3 = vf2{0.f, 0.f};                         \
        uu0 = pkfma(wih[0],  vf2{q0.x, q0.y}, uu0);                           \
        uu1 = pkfma(wih[1],  vf2{q0.z, q0.w}, uu1);                           \
        uu2 = pkfma(wih[2],  vf2{q1.x, q1.y}, uu2);                           \
        uu3 = pkfma(wih[3],  vf2{q1.z, q1.w}, uu3);                           \
        uu0 = pkfma(wih[4],  vf2{q2.x, q2.y}, uu0);                           \
        uu1 = pkfma(wih[5],  vf2{q2.z, q2.w}, uu1);                           \
        uu2 = pkfma(wih[6],  vf2{q3.x, q3.y}, uu2);                           \
        uu3 = pkfma(wih[7],  vf2{q3.z, q3.w}, uu3);                           \
        uu0 = pkfma(wih[8],  vf2{q4.x, q4.y}, uu0);                           \
        uu1 = pkfma(wih[9],  vf2{q4.z, q4.w}, uu1);                           \
        uu2 = pkfma(wih[10], vf2{q5.x, q5.y}, uu2);                           \
        uu3 = pkfma(wih[11], vf2{q5.z, q5.w}, uu3);                           \
        uu0 = pkfma(wih[12], vf2{q6.x, q6.y}, uu0);                           \
        uu1 = pkfma(wih[13], vf2{q6.z, q6.w}, uu1);                           \
        uu2 = pkfma(wih[14], vf2{q7.x, q7.y}, uu2);                           \
        uu3 = pkfma(wih[15], vf2{q7.z, q7.w}, uu3);                           \
        const vf2 uS = (uu0 + uu1) + (uu2 + uu3);                             \
        DST = uS.x + uS.y;                                                    \
    }

    float cu0, cu1, cu2, cu3, cu4, cu5, cu6, cu7;
    UHALF(cu0, &xbuf[0][0][xh])
    UHALF(cu1, &xbuf[0][1][xh])
    UHALF(cu2, &xbuf[0][2][xh])
    UHALF(cu3, &xbuf[0][3][xh])
    UHALF(cu4, &xbuf[0][4][xh])
    UHALF(cu5, &xbuf[0][5][xh])
    UHALF(cu6, &xbuf[0][6][xh])
    UHALF(cu7, &xbuf[0][7][xh])

    __syncthreads();   // protect xbuf[0] reads from chunk-0's overwrite

#define RNN_STEP(HRD, HWR, UVAL, NXV, KIDX)                                   \
    {                                                                         \
        const float uu = dpp_xadd<0x141>(UVAL) + badd;  /* merge dup pair */  \
        /* u half-dot for next chunk, step KIDX (off critical path) */        \
        UHALF(NXV, xsrc + (KIDX) * I_DIM + xh)                                \
        const float4* hv = reinterpret_cast<const float4*>(HRD);              \
        vf2 a0 = vf2{0.f, 0.f}, b0 = vf2{0.f, 0.f};                           \
        vf2 a1 = vf2{0.f, 0.f}, b1 = vf2{0.f, 0.f};                           \
        vf2 a2 = vf2{0.f, 0.f}, b2 = vf2{0.f, 0.f};                           \
        vf2 a3 = vf2{0.f, 0.f}, b3 = vf2{0.f, 0.f};                           \
        _Pragma("unroll")                                                     \
        for (int m = 0; m < 8; ++m) {                                         \
            const float4 h4 = hv[8 * m + p];                                  \
            const vf2 hlo = vf2{h4.x, h4.y};                                  \
            const vf2 hhi = vf2{h4.z, h4.w};                                  \
            a0 = pkfma(w2[0][2 * m], hlo, a0);                                \
            b0 = pkfma(w2[0][2 * m + 1], hhi, b0);                            \
            a1 = pkfma(w2[1][2 * m], hlo, a1);                                \
            b1 = pkfma(w2[1][2 * m + 1], hhi, b1);                            \
            a2 = pkfma(w2[2][2 * m], hlo, a2);                                \
            b2 = pkfma(w2[2][2 * m + 1], hhi, b2);                            \
            a3 = pkfma(w2[3][2 * m], hlo, a3);                                \
            b3 = pkfma(w2[3][2 * m + 1], hhi, b3);                            \
        }                                                                     \
        const vf2 s0v = a0 + b0, s1v = a1 + b1;                               \
        const vf2 s2v = a2 + b2, s3v = a3 + b3;                               \
        const float d0 = s0v.x + s0v.y, d1 = s1v.x + s1v.y;                   \
        const float d2 = s2v.x + s2v.y, d3 = s3v.x + s3v.y;                   \
        const float e0 = dpp_xadd<0xB1>(d0);                                  \
        const float e1 = dpp_xadd<0xB1>(d1);                                  \
        const float e2 = dpp_xadd<0xB1>(d2);                                  \
        const float e3 = dpp_xadd<0xB1>(d3);                                  \
        const float c0 = sel1 ? e1 : e0;                                      \
        const float c1 = sel1 ? e3 : e2;                                      \
        const float f0 = dpp_xadd<0x4E>(c0);                                  \
        const float f1 = dpp_xadd<0x4E>(c1);                                  \
        const float gg = sel2 ? f1 : f0;                                      \
        const float fr = dpp_xadd<0x141>(gg);                                 \
        const float hval = fast_tanh(fr + uu);                                \
        if (wsel) { (HWR)[jown] = hval; *us = hval; }                         \
        us += H_DIM;                                                          \
        lds_barrier();                                                        \
    }

    for (int c = 0; c < NCHK; ++c) {
        // stage x chunk c+2 (in xreg_cur) into slot c&1; advance pipeline
        {
            float* xd = &xbuf[c & 1][0][0];
            xd[tid] = xreg_cur;
        }
        xreg_cur = xreg_nxt;
        {
            int tr = (c + 4) * CHK + (tid >> 6);
            if (tr > T_CNT - 1) tr = T_CNT - 1;
            xreg_nxt = inb[(size_t)tr * 65 + 1 + (tid & 63)];
        }
        const float* xsrc = &xbuf[(c + 1) & 1][0][0];

        float nx0, nx1, nx2, nx3, nx4, nx5, nx6, nx7;
        RNN_STEP(hA, hB, cu0, nx0, 0)
        RNN_STEP(hB, hA, cu1, nx1, 1)
        RNN_STEP(hA, hB, cu2, nx2, 2)
        RNN_STEP(hB, hA, cu3, nx3, 3)
        RNN_STEP(hA, hB, cu4, nx4, 4)
        RNN_STEP(hB, hA, cu5, nx5, 5)
        RNN_STEP(hA, hB, cu6, nx6, 6)
        RNN_STEP(hB, hA, cu7, nx7, 7)

        cu0 = nx0; cu1 = nx1; cu2 = nx2; cu3 = nx3;
        cu4 = nx4; cu5 = nx5; cu6 = nx6; cu7 = nx7;
    }
#undef RNN_STEP
#undef UHALF

    // ---- epilogue: sigma + log-lik from the (L2-hot) h trace ----
    asm volatile("s_waitcnt vmcnt(0)" ::: "memory");
    __threadfence();
    __syncthreads();

    const int wv   = tid >> 6;
    const int lane = tid & 63;
    const float4 wl =
        reinterpret_cast<const float4*>(W_lin + s * H_DIM)[lane];
    const float blin = b_lin[s];
    const float* feb = fe + (size_t)s * T_CNT;
    float* sig_out = out + 1 + (size_t)s * T_CNT;

    float ll = 0.f;
    for (int i = 0; i < T_CNT / 8; ++i) {
        const int t = i * 8 + wv;
        const float4 h4 =
            reinterpret_cast<const float4*>(Hb + (size_t)t * H_DIM)[lane];
        float d = fma4(wl, h4, 0.f);
#pragma unroll
        for (int m = 1; m <= 32; m <<= 1) d += __shfl_xor(d, m);
        if (lane == 0) {
            const float sigma = fabsf(d + blin);
            sig_out[t] = sigma;
            const float diff = inb[(size_t)t * 65] - feb[t];
            ll -= (diff * diff) / (2.f * sigma * sigma);
        }
    }
    if (lane == 0) red[wv] = ll;
    __syncthreads();
    if (tid == 0) {
        atomicAdd(out, ((red[0] + red[1]) + (red[2] + red[3])) +
                       ((red[4] + red[5]) + (red[6] + red[7])));
    }
}

// ---------------- fallback (no workspace): round-3 style, self-contained ----
__launch_bounds__(1024, 4)
__global__ void rnn_fallback_kernel(const float* __restrict__ input_data,
                                    const float* __restrict__ hidden,
                                    const float* __restrict__ fe,
                                    const float* __restrict__ W_ih,
                                    const float* __restrict__ W_hh,
                                    const float* __restrict__ b_ih,
                                    const float* __restrict__ b_hh,
                                    const float* __restrict__ W_lin,
                                    const float* __restrict__ b_lin,
                                    float* __restrict__ out)
{
    const int s    = blockIdx.x;
    const int tid  = threadIdx.x;
    const int j    = tid >> 2;
    const int q    = tid & 3;
    const int lane = tid & 63;
    const int wv   = tid >> 6;

    __shared__ float hbuf[2][H_DIM];
    __shared__ float zbuf[T_CNT];
    __shared__ float febuf[T_CNT];
    __shared__ float wlin_lds[H_DIM];
    __shared__ float wsum[2][16];
    __shared__ float xbuf[64][I_DIM];

    const float* in_base = input_data + (size_t)s * T_CNT * 65;
    const float* fe_base = fe + (size_t)s * T_CNT;

    for (int t = tid; t < T_CNT; t += 1024) {
        zbuf[t]  = in_base[(size_t)t * 65];
        febuf[t] = fe_base[t];
    }
    if (tid < H_DIM) {
        hbuf[1][tid]  = hidden[s * H_DIM + tid];
        wlin_lds[tid] = W_lin[s * H_DIM + tid];
    }

    float4 w[16];
    {
        const float4* wrow =
            reinterpret_cast<const float4*>(W_hh + ((size_t)s * H_DIM + j) * H_DIM);
#pragma unroll
        for (int m = 0; m < 16; ++m) w[m] = wrow[4 * m + q];
    }
    float4 wx[4];
    {
        const float4* wxrow =
            reinterpret_cast<const float4*>(W_ih + ((size_t)s * H_DIM + j) * I_DIM);
#pragma unroll
        for (int m = 0; m < 4; ++m) wx[m] = wxrow[4 * m + q];
    }
    const float badd = b_ih[s * H_DIM + j] + b_hh[s * H_DIM + j];
    const float blin = b_lin[s];
    float* sig_out = out + 1 + (size_t)s * T_CNT;

    float ll = 0.f, sv_prev = 0.f;
    __syncthreads();

    for (int c = 0; c < T_CNT / 64; ++c) {
        for (int idx = tid; idx < 64 * I_DIM; idx += 1024) {
            const int row = idx >> 6, col = idx & 63;
            xbuf[row][col] = in_base[(size_t)(c * 64 + row) * 65 + 1 + col];
        }
        __syncthreads();
        for (int tt = 0; tt < 64; ++tt) {
            const int t  = c * 64 + tt;
            const int rp = (t + 1) & 1;
            {
                float sv = sv_prev;
                sv += __shfl_xor(sv, 4);
                sv += __shfl_xor(sv, 8);
                sv += __shfl_xor(sv, 16);
                sv += __shfl_xor(sv, 32);
                if (lane == 0) wsum[(t - 1) & 1][wv] = sv;
            }
            if (tid == 0 && t >= 2) {
                const int tm = t - 2;
                const float* wp = wsum[tm & 1];
                float sg = (((wp[0] + wp[1]) + (wp[2] + wp[3])) +
                            ((wp[4] + wp[5]) + (wp[6] + wp[7]))) +
                           (((wp[8] + wp[9]) + (wp[10] + wp[11])) +
                            ((wp[12] + wp[13]) + (wp[14] + wp[15]))) + blin;
                const float sigma = fabsf(sg);
                sig_out[tm] = sigma;
                const float diff = zbuf[tm] - febuf[tm];
                ll -= (diff * diff) / (2.f * sigma * sigma);
            }
            const float4* hv = reinterpret_cast<const float4*>(&hbuf[rp][0]);
            float a0 = 0.f, a1 = 0.f, a2 = 0.f, a3 = 0.f;
#pragma unroll
            for (int m = 0; m < 16; m += 4) {
                a0 = fma4(w[m],     hv[4 * (m + 0) + q], a0);
                a1 = fma4(w[m + 1], hv[4 * (m + 1) + q], a1);
                a2 = fma4(w[m + 2], hv[4 * (m + 2) + q], a2);
                a3 = fma4(w[m + 3], hv[4 * (m + 3) + q], a3);
            }
            const float4* xv = reinterpret_cast<const float4*>(&xbuf[tt][0]);
#pragma unroll
            for (int m = 0; m < 4; ++m) a0 = fma4(wx[m], xv[4 * m + q], a0);

            float dot = (a0 + a1) + (a2 + a3);
            dot += __shfl_xor(dot, 1);
            dot += __shfl_xor(dot, 2);
            const float h = fast_tanh(dot + badd);
            if (q == 0) hbuf[t & 1][j] = h;
            sv_prev = h * wlin_lds[j];
            __syncthreads();
        }
        __syncthreads();
    }
    {
        float sv = sv_prev;
        sv += __shfl_xor(sv, 4);
        sv += __shfl_xor(sv, 8);
        sv += __shfl_xor(sv, 16);
        sv += __shfl_xor(sv, 32);
        if (lane == 0) wsum[(T_CNT - 1) & 1][wv] = sv;
    }
    __syncthreads();
    if (tid == 0) {
        for (int tm = T_CNT - 2; tm < T_CNT; ++tm) {
            const float* wp = wsum[tm & 1];
            float sg = (((wp[0] + wp[1]) + (wp[2] + wp[3])) +
                        ((wp[4] + wp[5]) + (wp[6] + wp[7]))) +
                       (((wp[8] + wp[9]) + (wp[10] + wp[11])) +
                        ((wp[12] + wp[13]) + (wp[14] + wp[15]))) + blin;
            const float sigma = fabsf(sg);
            sig_out[tm] = sigma;
            const float diff = zbuf[tm] - febuf[tm];
            ll -= (diff * diff) / (2.f * sigma * sigma);
        }
        atomicAdd(out, ll);
    }
}

extern "C" void kernel_launch(void* const* d_in, const int* in_sizes, int n_in,
                              void* d_out, int out_size, void* d_ws, size_t ws_size,
                              hipStream_t stream) {
    (void)in_sizes; (void)n_in; (void)out_size;
    const float* input_data = (const float*)d_in[0];
    const float* hidden     = (const float*)d_in[1];
    const float* fe         = (const float*)d_in[2];
    const float* W_ih       = (const float*)d_in[3];
    const float* W_hh       = (const float*)d_in[4];
    const float* b_ih       = (const float*)d_in[5];
    const float* b_hh       = (const float*)d_in[6];
    const float* W_lin      = (const float*)d_in[7];
    const float* b_lin      = (const float*)d_in[8];
    float* out = (float*)d_out;

    hipMemsetAsync(d_out, 0, sizeof(float), stream);

    const size_t h_bytes = (size_t)S_CNT * T_CNT * H_DIM * sizeof(float);

    if (ws_size >= h_bytes) {
        float* Hb = (float*)d_ws;
        rnn_fused<<<dim3(S_CNT), dim3(512), 0, stream>>>(
            input_data, hidden, fe, W_ih, W_hh, b_ih, b_hh, W_lin, b_lin,
            Hb, out);
    } else {
        rnn_fallback_kernel<<<dim3(S_CNT), dim3(1024), 0, stream>>>(
            input_data, hidden, fe, W_ih, W_hh, b_ih, b_hh, W_lin, b_lin, out);
    }
}

// Round 16
// 1627.378 us; speedup vs baseline: 4.2519x; 4.2519x over previous
//
#include <hip/hip_runtime.h>
#include <cmath>

#define S_CNT 50
#define T_CNT 2048
#define I_DIM 64
#define H_DIM 256
#define CHK   8            // timesteps per u-register chunk
#define NCHK  (T_CNT / CHK)

typedef float vf2 __attribute__((ext_vector_type(2)));

__device__ __forceinline__ float fast_tanh(float x) {
    float e = __expf(2.0f * x);
    return 1.0f - __fdividef(2.0f, e + 1.0f);
}

__device__ __forceinline__ vf2 pkfma(vf2 a, vf2 b, vf2 c) {
#if __has_builtin(__builtin_elementwise_fma)
    return __builtin_elementwise_fma(a, b, c);
#else
    vf2 r; r.x = fmaf(a.x, b.x, c.x); r.y = fmaf(a.y, b.y, c.y); return r;
#endif
}

__device__ __forceinline__ float fma4(const float4 w, const float4 h, float a) {
    a = fmaf(w.x, h.x, a);
    a = fmaf(w.y, h.y, a);
    a = fmaf(w.z, h.z, a);
    a = fmaf(w.w, h.w, a);
    return a;
}

// x + DPP(x): VALU-pipe cross-lane add. CTRLs: 0xB1 quad xor1, 0x4E quad
// xor2, 0x141 row_half_mirror (lane^7 within each 8-lane half-row).
template <int CTRL>
__device__ __forceinline__ float dpp_xadd(float x) {
    const int xi = __float_as_int(x);
    const int yi = __builtin_amdgcn_update_dpp(xi, xi, CTRL, 0xF, 0xF, false);
    return x + __int_as_float(yi);
}

// Barrier that drains ONLY LDS (lgkmcnt), leaving global loads/stores in
// flight (vmcnt never drained in-loop). Verified race-free r10/r12.
__device__ __forceinline__ void lds_barrier() {
    __builtin_amdgcn_sched_barrier(0);
    asm volatile("s_waitcnt lgkmcnt(0)");
    __builtin_amdgcn_s_barrier();
    __builtin_amdgcn_sched_barrier(0);
}

// U[s][t][j] = b_ih[s][j] + b_hh[s][j] + W_ih[s][j]·x[s][t]
__launch_bounds__(256, 4)
__global__ void precompute_u_kernel(const float* __restrict__ input_data,
                                    const float* __restrict__ W_ih,
                                    const float* __restrict__ b_ih,
                                    const float* __restrict__ b_hh,
                                    float* __restrict__ U)
{
    const int s  = blockIdx.x;
    const int tb = blockIdx.y;   // 64 t-slices of 32 steps
    const int j  = threadIdx.x;

    float4 w[16];
    const float4* wrow =
        reinterpret_cast<const float4*>(W_ih + ((size_t)s * H_DIM + j) * I_DIM);
#pragma unroll
    for (int k = 0; k < 16; ++k) w[k] = wrow[k];
    const float bsum = b_ih[s * H_DIM + j] + b_hh[s * H_DIM + j];

    __shared__ float xs[32][I_DIM];
    const float* inb = input_data + (size_t)s * T_CNT * 65;
    float* Ub = U + (size_t)s * T_CNT * H_DIM;

    const int t0 = tb * 32;
    for (int idx = j; idx < 32 * I_DIM; idx += 256) {
        const int row = idx >> 6, col = idx & 63;
        xs[row][col] = inb[(size_t)(t0 + row) * 65 + 1 + col];
    }
    __syncthreads();
    for (int tt = 0; tt < 32; ++tt) {
        const float4* xv = reinterpret_cast<const float4*>(&xs[tt][0]);
        float a0 = bsum, a1 = 0.f, a2 = 0.f, a3 = 0.f;
#pragma unroll
        for (int k = 0; k < 16; k += 4) {
            a0 = fma4(w[k],     xv[k],     a0);
            a1 = fma4(w[k + 1], xv[k + 1], a1);
            a2 = fma4(w[k + 2], xv[k + 2], a2);
            a3 = fma4(w[k + 3], xv[k + 3], a3);
        }
        Ub[(size_t)(t0 + tt) * H_DIM + j] = (a0 + a1) + (a2 + a3);
    }
}

// Main recurrence + fused sigma/log-lik epilogue. Loop body is EXACT r12
// (best measured: 1160 us): 512 threads, tid = g*8+p, all-DPP reduce
// xor1 -> sel(s1=b0^b2) -> xor2 -> sel(s2=b0^b1) -> xor7(row_half_mirror),
// u from registers (8-step double-buffered chunks), lgkm-only barrier.
// After the loop: __syncthreads() (drains vmcnt; same-CU store->load needs
// no device fence — r15's __threadfence caused a 4 GB L2-flush storm) then
// the r15-verified epilogue computes sigma and the log-lik reduction.
__global__
__launch_bounds__(512)
__attribute__((amdgpu_waves_per_eu(1, 2)))
void rnn_main12(const float* __restrict__ input_data,
                const float* __restrict__ hidden,
                const float* __restrict__ fe,
                const float* __restrict__ W_hh,
                const float* __restrict__ W_lin,
                const float* __restrict__ b_lin,
                float* __restrict__ U,     // consumed, then reused as H-out
                float* __restrict__ out)
{
    const int s    = blockIdx.x;
    const int tid  = threadIdx.x;
    const int g    = tid >> 3;    // 0..63: row group (rows 4g..4g+3)
    const int p    = tid & 7;     // col slice

    const int s1 = (p ^ (p >> 2)) & 1;
    const int s2 = (p ^ (p >> 1)) & 1;
    const int jr = s1 + 2 * s2;
    const int jown = 4 * g + jr;

    __shared__ __align__(16) float hA[H_DIM];
    __shared__ __align__(16) float hB[H_DIM];
    __shared__ float red[8];

    if (tid < H_DIM) hA[tid] = hidden[s * H_DIM + tid];

    // weights: 4 rows x 8 chunks of float4 (f = 8m+p), as packed vf2 pairs
    vf2 w2[4][16];
#pragma unroll
    for (int r = 0; r < 4; ++r) {
        const float4* wrow = reinterpret_cast<const float4*>(
            W_hh + ((size_t)s * H_DIM + 4 * g + r) * H_DIM);
#pragma unroll
        for (int m = 0; m < 8; ++m) {
            const float4 wv = wrow[8 * m + p];
            w2[r][2 * m]     = vf2{wv.x, wv.y};
            w2[r][2 * m + 1] = vf2{wv.z, wv.w};
        }
    }

    float* Ub = U + (size_t)s * T_CNT * H_DIM;
    float* us = Ub + jown;                 // h store ptr (advances H_DIM/step)

    // prologue: chunk 0 of u into registers
    const float* u0 = Ub + jown;
    float cu0 = u0[0 * H_DIM], cu1 = u0[1 * H_DIM];
    float cu2 = u0[2 * H_DIM], cu3 = u0[3 * H_DIM];
    float cu4 = u0[4 * H_DIM], cu5 = u0[5 * H_DIM];
    float cu6 = u0[6 * H_DIM], cu7 = u0[7 * H_DIM];
    const float* up = Ub + jown + CHK * H_DIM;   // chunk 1

    const bool wsel = (p < 4);
    const bool sel1 = (s1 != 0);
    const bool sel2 = (s2 != 0);

    __syncthreads();

#define RNN_STEP(HRD, HWR, UVAL)                                              \
    {                                                                         \
        const float4* hv = reinterpret_cast<const float4*>(HRD);              \
        vf2 a0 = vf2{0.f, 0.f}, b0 = vf2{0.f, 0.f};                           \
        vf2 a1 = vf2{0.f, 0.f}, b1 = vf2{0.f, 0.f};                           \
        vf2 a2 = vf2{0.f, 0.f}, b2 = vf2{0.f, 0.f};                           \
        vf2 a3 = vf2{0.f, 0.f}, b3 = vf2{0.f, 0.f};                           \
        _Pragma("unroll")                                                     \
        for (int m = 0; m < 8; ++m) {                                         \
            const float4 h4 = hv[8 * m + p];                                  \
            const vf2 hlo = vf2{h4.x, h4.y};                                  \
            const vf2 hhi = vf2{h4.z, h4.w};                                  \
            a0 = pkfma(w2[0][2 * m], hlo, a0);                                \
            b0 = pkfma(w2[0][2 * m + 1], hhi, b0);                            \
            a1 = pkfma(w2[1][2 * m], hlo, a1);                                \
            b1 = pkfma(w2[1][2 * m + 1], hhi, b1);                            \
            a2 = pkfma(w2[2][2 * m], hlo, a2);                                \
            b2 = pkfma(w2[2][2 * m + 1], hhi, b2);                            \
            a3 = pkfma(w2[3][2 * m], hlo, a3);                                \
            b3 = pkfma(w2[3][2 * m + 1], hhi, b3);                            \
        }                                                                     \
        const vf2 s0v = a0 + b0, s1v = a1 + b1;                               \
        const vf2 s2v = a2 + b2, s3v = a3 + b3;                               \
        const float d0 = s0v.x + s0v.y, d1 = s1v.x + s1v.y;                   \
        const float d2 = s2v.x + s2v.y, d3 = s3v.x + s3v.y;                   \
        /* xor1 (quad DPP) */                                                 \
        const float e0 = dpp_xadd<0xB1>(d0);                                  \
        const float e1 = dpp_xadd<0xB1>(d1);                                  \
        const float e2 = dpp_xadd<0xB1>(d2);                                  \
        const float e3 = dpp_xadd<0xB1>(d3);                                  \
        /* select by s1 = b0^b2 (invariant under ^2 and ^7) */                \
        const float c0 = sel1 ? e1 : e0;                                      \
        const float c1 = sel1 ? e3 : e2;                                      \
        /* xor2 (quad DPP) */                                                 \
        const float f0 = dpp_xadd<0x4E>(c0);                                  \
        const float f1 = dpp_xadd<0x4E>(c1);                                  \
        /* select by s2 = b0^b1 (invariant under ^7) */                       \
        const float gg = sel2 ? f1 : f0;                                      \
        /* xor7 via row_half_mirror DPP: full row sum, dup at p^7 */          \
        const float fr = dpp_xadd<0x141>(gg);                                 \
        const float hval = fast_tanh(fr + (UVAL));                            \
        if (wsel) { (HWR)[jown] = hval; *us = hval; }                         \
        us += H_DIM;                                                          \
        lds_barrier();                                                        \
    }

    for (int c = 0; c < NCHK; ++c) {
        // issue next-chunk u loads (consumed >= 8 steps later)
        const float nx0 = up[0 * H_DIM], nx1 = up[1 * H_DIM];
        const float nx2 = up[2 * H_DIM], nx3 = up[3 * H_DIM];
        const float nx4 = up[4 * H_DIM], nx5 = up[5 * H_DIM];
        const float nx6 = up[6 * H_DIM], nx7 = up[7 * H_DIM];

        RNN_STEP(hA, hB, cu0)
        RNN_STEP(hB, hA, cu1)
        RNN_STEP(hA, hB, cu2)
        RNN_STEP(hB, hA, cu3)
        RNN_STEP(hA, hB, cu4)
        RNN_STEP(hB, hA, cu5)
        RNN_STEP(hA, hB, cu6)
        RNN_STEP(hB, hA, cu7)

        cu0 = nx0; cu1 = nx1; cu2 = nx2; cu3 = nx3;
        cu4 = nx4; cu5 = nx5; cu6 = nx6; cu7 = nx7;
        if (c < NCHK - 2) up += CHK * H_DIM;   // stay on last chunk (no OOB)
    }
#undef RNN_STEP

    // ---- fused epilogue: sigma + log-lik from the (L2/L3-hot) h trace ----
    // __syncthreads() drains vmcnt(0)+lgkmcnt(0): all h stores visible to
    // this CU's reads via L2. No device fence (r15 lesson: threadfence ->
    // L2 flush storm, 4 GB of writes).
    __syncthreads();

    const int wv   = tid >> 6;
    const int lane = tid & 63;
    const float4 wl =
        reinterpret_cast<const float4*>(W_lin + s * H_DIM)[lane];
    const float blin = b_lin[s];
    const float* inb = input_data + (size_t)s * T_CNT * 65;
    const float* feb = fe + (size_t)s * T_CNT;
    float* sig_out = out + 1 + (size_t)s * T_CNT;

    float ll = 0.f;
    for (int i = 0; i < T_CNT / 8; ++i) {
        const int t = i * 8 + wv;
        const float4 h4 =
            reinterpret_cast<const float4*>(Ub + (size_t)t * H_DIM)[lane];
        float d = fma4(wl, h4, 0.f);
#pragma unroll
        for (int m = 1; m <= 32; m <<= 1) d += __shfl_xor(d, m);
        if (lane == 0) {
            const float sigma = fabsf(d + blin);
            sig_out[t] = sigma;
            const float diff = inb[(size_t)t * 65] - feb[t];
            ll -= (diff * diff) / (2.f * sigma * sigma);
        }
    }
    if (lane == 0) red[wv] = ll;
    __syncthreads();
    if (tid == 0) {
        atomicAdd(out, ((red[0] + red[1]) + (red[2] + red[3])) +
                       ((red[4] + red[5]) + (red[6] + red[7])));
    }
}

// ---------------- fallback (no workspace): round-3 style, self-contained ----
__launch_bounds__(1024, 4)
__global__ void rnn_fallback_kernel(const float* __restrict__ input_data,
                                    const float* __restrict__ hidden,
                                    const float* __restrict__ fe,
                                    const float* __restrict__ W_ih,
                                    const float* __restrict__ W_hh,
                                    const float* __restrict__ b_ih,
                                    const float* __restrict__ b_hh,
                                    const float* __restrict__ W_lin,
                                    const float* __restrict__ b_lin,
                                    float* __restrict__ out)
{
    const int s    = blockIdx.x;
    const int tid  = threadIdx.x;
    const int j    = tid >> 2;
    const int q    = tid & 3;
    const int lane = tid & 63;
    const int wv   = tid >> 6;

    __shared__ float hbuf[2][H_DIM];
    __shared__ float zbuf[T_CNT];
    __shared__ float febuf[T_CNT];
    __shared__ float wlin_lds[H_DIM];
    __shared__ float wsum[2][16];
    __shared__ float xbuf[64][I_DIM];

    const float* in_base = input_data + (size_t)s * T_CNT * 65;
    const float* fe_base = fe + (size_t)s * T_CNT;

    for (int t = tid; t < T_CNT; t += 1024) {
        zbuf[t]  = in_base[(size_t)t * 65];
        febuf[t] = fe_base[t];
    }
    if (tid < H_DIM) {
        hbuf[1][tid]  = hidden[s * H_DIM + tid];
        wlin_lds[tid] = W_lin[s * H_DIM + tid];
    }

    float4 w[16];
    {
        const float4* wrow =
            reinterpret_cast<const float4*>(W_hh + ((size_t)s * H_DIM + j) * H_DIM);
#pragma unroll
        for (int m = 0; m < 16; ++m) w[m] = wrow[4 * m + q];
    }
    float4 wx[4];
    {
        const float4* wxrow =
            reinterpret_cast<const float4*>(W_ih + ((size_t)s * H_DIM + j) * I_DIM);
#pragma unroll
        for (int m = 0; m < 4; ++m) wx[m] = wxrow[4 * m + q];
    }
    const float badd = b_ih[s * H_DIM + j] + b_hh[s * H_DIM + j];
    const float blin = b_lin[s];
    float* sig_out = out + 1 + (size_t)s * T_CNT;

    float ll = 0.f, sv_prev = 0.f;
    __syncthreads();

    for (int c = 0; c < T_CNT / 64; ++c) {
        for (int idx = tid; idx < 64 * I_DIM; idx += 1024) {
            const int row = idx >> 6, col = idx & 63;
            xbuf[row][col] = in_base[(size_t)(c * 64 + row) * 65 + 1 + col];
        }
        __syncthreads();
        for (int tt = 0; tt < 64; ++tt) {
            const int t  = c * 64 + tt;
            const int rp = (t + 1) & 1;
            {
                float sv = sv_prev;
                sv += __shfl_xor(sv, 4);
                sv += __shfl_xor(sv, 8);
                sv += __shfl_xor(sv, 16);
                sv += __shfl_xor(sv, 32);
                if (lane == 0) wsum[(t - 1) & 1][wv] = sv;
            }
            if (tid == 0 && t >= 2) {
                const int tm = t - 2;
                const float* wp = wsum[tm & 1];
                float sg = (((wp[0] + wp[1]) + (wp[2] + wp[3])) +
                            ((wp[4] + wp[5]) + (wp[6] + wp[7]))) +
                           (((wp[8] + wp[9]) + (wp[10] + wp[11])) +
                            ((wp[12] + wp[13]) + (wp[14] + wp[15]))) + blin;
                const float sigma = fabsf(sg);
                sig_out[tm] = sigma;
                const float diff = zbuf[tm] - febuf[tm];
                ll -= (diff * diff) / (2.f * sigma * sigma);
            }
            const float4* hv = reinterpret_cast<const float4*>(&hbuf[rp][0]);
            float a0 = 0.f, a1 = 0.f, a2 = 0.f, a3 = 0.f;
#pragma unroll
            for (int m = 0; m < 16; m += 4) {
                a0 = fma4(w[m],     hv[4 * (m + 0) + q], a0);
                a1 = fma4(w[m + 1], hv[4 * (m + 1) + q], a1);
                a2 = fma4(w[m + 2], hv[4 * (m + 2) + q], a2);
                a3 = fma4(w[m + 3], hv[4 * (m + 3) + q], a3);
            }
            const float4* xv = reinterpret_cast<const float4*>(&xbuf[tt][0]);
#pragma unroll
            for (int m = 0; m < 4; ++m) a0 = fma4(wx[m], xv[4 * m + q], a0);

            float dot = (a0 + a1) + (a2 + a3);
            dot += __shfl_xor(dot, 1);
            dot += __shfl_xor(dot, 2);
            const float h = fast_tanh(dot + badd);
            if (q == 0) hbuf[t & 1][j] = h;
            sv_prev = h * wlin_lds[j];
            __syncthreads();
        }
        __syncthreads();
    }
    {
        float sv = sv_prev;
        sv += __shfl_xor(sv, 4);
        sv += __shfl_xor(sv, 8);
        sv += __shfl_xor(sv, 16);
        sv += __shfl_xor(sv, 32);
        if (lane == 0) wsum[(T_CNT - 1) & 1][wv] = sv;
    }
    __syncthreads();
    if (tid == 0) {
        for (int tm = T_CNT - 2; tm < T_CNT; ++tm) {
            const float* wp = wsum[tm & 1];
            float sg = (((wp[0] + wp[1]) + (wp[2] + wp[3])) +
                        ((wp[4] + wp[5]) + (wp[6] + wp[7]))) +
                       (((wp[8] + wp[9]) + (wp[10] + wp[11])) +
                        ((wp[12] + wp[13]) + (wp[14] + wp[15]))) + blin;
            const float sigma = fabsf(sg);
            sig_out[tm] = sigma;
            const float diff = zbuf[tm] - febuf[tm];
            ll -= (diff * diff) / (2.f * sigma * sigma);
        }
        atomicAdd(out, ll);
    }
}

extern "C" void kernel_launch(void* const* d_in, const int* in_sizes, int n_in,
                              void* d_out, int out_size, void* d_ws, size_t ws_size,
                              hipStream_t stream) {
    (void)in_sizes; (void)n_in; (void)out_size;
    const float* input_data = (const float*)d_in[0];
    const float* hidden     = (const float*)d_in[1];
    const float* fe         = (const float*)d_in[2];
    const float* W_ih       = (const float*)d_in[3];
    const float* W_hh       = (const float*)d_in[4];
    const float* b_ih       = (const float*)d_in[5];
    const float* b_hh       = (const float*)d_in[6];
    const float* W_lin      = (const float*)d_in[7];
    const float* b_lin      = (const float*)d_in[8];
    float* out = (float*)d_out;

    hipMemsetAsync(d_out, 0, sizeof(float), stream);

    const size_t u_bytes = (size_t)S_CNT * T_CNT * H_DIM * sizeof(float);

    if (ws_size >= u_bytes) {
        float* U = (float*)d_ws;
        precompute_u_kernel<<<dim3(S_CNT, 64), 256, 0, stream>>>(
            input_data, W_ih, b_ih, b_hh, U);
        rnn_main12<<<dim3(S_CNT), dim3(512), 0, stream>>>(
            input_data, hidden, fe, W_hh, W_lin, b_lin, U, out);
    } else {
        rnn_fallback_kernel<<<dim3(S_CNT), dim3(1024), 0, stream>>>(
            input_data, hidden, fe, W_ih, W_hh, b_ih, b_hh, W_lin, b_lin, out);
    }
}

// Round 17
// 1253.935 us; speedup vs baseline: 5.5182x; 1.2978x over previous
//
#include <hip/hip_runtime.h>
#include <cmath>

#define S_CNT 50
#define T_CNT 2048
#define I_DIM 64
#define H_DIM 256
#define CHK   8            // timesteps per u-register chunk
#define NCHK  (T_CNT / CHK)

typedef float vf2 __attribute__((ext_vector_type(2)));

__device__ __forceinline__ float fast_tanh(float x) {
    float e = __expf(2.0f * x);
    return 1.0f - __fdividef(2.0f, e + 1.0f);
}

__device__ __forceinline__ vf2 pkfma(vf2 a, vf2 b, vf2 c) {
#if __has_builtin(__builtin_elementwise_fma)
    return __builtin_elementwise_fma(a, b, c);
#else
    vf2 r; r.x = fmaf(a.x, b.x, c.x); r.y = fmaf(a.y, b.y, c.y); return r;
#endif
}

__device__ __forceinline__ float fma4(const float4 w, const float4 h, float a) {
    a = fmaf(w.x, h.x, a);
    a = fmaf(w.y, h.y, a);
    a = fmaf(w.z, h.z, a);
    a = fmaf(w.w, h.w, a);
    return a;
}

// x + DPP(x): VALU-pipe cross-lane add. CTRLs: 0xB1 quad xor1, 0x4E quad
// xor2, 0x141 row_half_mirror (lane^7 within each 8-lane half-row).
template <int CTRL>
__device__ __forceinline__ float dpp_xadd(float x) {
    const int xi = __float_as_int(x);
    const int yi = __builtin_amdgcn_update_dpp(xi, xi, CTRL, 0xF, 0xF, false);
    return x + __int_as_float(yi);
}

// Barrier that drains ONLY LDS (lgkmcnt), leaving global loads/stores in
// flight (vmcnt never drained in-loop). Verified race-free r10/r12.
__device__ __forceinline__ void lds_barrier() {
    __builtin_amdgcn_sched_barrier(0);
    asm volatile("s_waitcnt lgkmcnt(0)");
    __builtin_amdgcn_s_barrier();
    __builtin_amdgcn_sched_barrier(0);
}

// U[s][t][j] = b_ih[s][j] + b_hh[s][j] + W_ih[s][j]·x[s][t]
// v3: 2 rows/thread (jj, jj+128) share every x broadcast read -> DS reads
// per output halved (16 -> 8). Block = 64 timesteps (2 slices x 32), 256
// threads, grid (50,32). waves_per_eu(1,2) gives a 256-VGPR budget so the
// 128-float W array + accumulators do NOT spill (r15 lesson: spill shows
// as GB-scale WRITE_SIZE).
__global__
__launch_bounds__(256)
__attribute__((amdgpu_waves_per_eu(1, 2)))
void precompute_v3(const float* __restrict__ input_data,
                   const float* __restrict__ W_ih,
                   const float* __restrict__ b_ih,
                   const float* __restrict__ b_hh,
                   float* __restrict__ U)
{
    const int s   = blockIdx.x;
    const int tb  = blockIdx.y;   // 32 slices of 64 timesteps
    const int tid = threadIdx.x;
    const int ts  = tid >> 7;     // 0/1: which 32-t half this thread computes
    const int jj  = tid & 127;    // owns rows jj and jj+128

    __shared__ float xs[64][I_DIM];   // 16 KB
    const float* inb = input_data + (size_t)s * T_CNT * 65;
    float* Ub = U + (size_t)s * T_CNT * H_DIM;
    const int t0 = tb * 64;

    // stage 64 timesteps of x (coalesced)
    for (int idx = tid; idx < 64 * I_DIM; idx += 256) {
        const int row = idx >> 6, col = idx & 63;
        xs[row][col] = inb[(size_t)(t0 + row) * 65 + 1 + col];
    }

    // weights for rows jj and jj+128, vf2-packed (128 VGPRs)
    vf2 wa[32], wb[32];
    {
        const float4* ra = reinterpret_cast<const float4*>(
            W_ih + ((size_t)s * H_DIM + jj) * I_DIM);
        const float4* rb = reinterpret_cast<const float4*>(
            W_ih + ((size_t)s * H_DIM + jj + 128) * I_DIM);
#pragma unroll
        for (int k = 0; k < 16; ++k) {
            const float4 va = ra[k], vb = rb[k];
            wa[2 * k]     = vf2{va.x, va.y};
            wa[2 * k + 1] = vf2{va.z, va.w};
            wb[2 * k]     = vf2{vb.x, vb.y};
            wb[2 * k + 1] = vf2{vb.z, vb.w};
        }
    }
    const float ba = b_ih[s * H_DIM + jj] + b_hh[s * H_DIM + jj];
    const float bb = b_ih[s * H_DIM + jj + 128] + b_hh[s * H_DIM + jj + 128];

    __syncthreads();

    for (int tt = 0; tt < 32; ++tt) {
        const int t = t0 + ts * 32 + tt;
        const float4* xv =
            reinterpret_cast<const float4*>(&xs[ts * 32 + tt][0]);
        vf2 aa0 = vf2{0.f, 0.f}, aa1 = vf2{0.f, 0.f};
        vf2 ab0 = vf2{0.f, 0.f}, ab1 = vf2{0.f, 0.f};
#pragma unroll
        for (int k = 0; k < 16; ++k) {
            const float4 q = xv[k];
            const vf2 lo = vf2{q.x, q.y};
            const vf2 hi = vf2{q.z, q.w};
            aa0 = pkfma(wa[2 * k],     lo, aa0);
            aa1 = pkfma(wa[2 * k + 1], hi, aa1);
            ab0 = pkfma(wb[2 * k],     lo, ab0);
            ab1 = pkfma(wb[2 * k + 1], hi, ab1);
        }
        const vf2 sa = aa0 + aa1, sb = ab0 + ab1;
        Ub[(size_t)t * H_DIM + jj]       = ba + sa.x + sa.y;
        Ub[(size_t)t * H_DIM + jj + 128] = bb + sb.x + sb.y;
    }
}

// Main recurrence — EXACT r12 (best measured: 1160 us). 512 threads,
// tid = g*8+p, all-DPP reduce xor1 -> sel(s1=b0^b2) -> xor2 ->
// sel(s2=b0^b1) -> xor7(row_half_mirror). u from registers (8-step
// double-buffered chunks); lgkm-only barrier per step.
__global__
__launch_bounds__(512)
__attribute__((amdgpu_waves_per_eu(1, 2)))
void rnn_main9(const float* __restrict__ hidden,
               const float* __restrict__ W_hh,
               float* __restrict__ U)   // consumed, then reused as H-out
{
    const int s    = blockIdx.x;
    const int tid  = threadIdx.x;
    const int g    = tid >> 3;    // 0..63: row group (rows 4g..4g+3)
    const int p    = tid & 7;     // col slice

    const int s1 = (p ^ (p >> 2)) & 1;
    const int s2 = (p ^ (p >> 1)) & 1;
    const int jr = s1 + 2 * s2;
    const int jown = 4 * g + jr;

    __shared__ __align__(16) float hA[H_DIM];
    __shared__ __align__(16) float hB[H_DIM];

    if (tid < H_DIM) hA[tid] = hidden[s * H_DIM + tid];

    // weights: 4 rows x 8 chunks of float4 (f = 8m+p), as packed vf2 pairs
    vf2 w2[4][16];
#pragma unroll
    for (int r = 0; r < 4; ++r) {
        const float4* wrow = reinterpret_cast<const float4*>(
            W_hh + ((size_t)s * H_DIM + 4 * g + r) * H_DIM);
#pragma unroll
        for (int m = 0; m < 8; ++m) {
            const float4 wv = wrow[8 * m + p];
            w2[r][2 * m]     = vf2{wv.x, wv.y};
            w2[r][2 * m + 1] = vf2{wv.z, wv.w};
        }
    }

    float* Ub = U + (size_t)s * T_CNT * H_DIM;
    float* us = Ub + jown;                 // h store ptr (advances H_DIM/step)

    // prologue: chunk 0 of u into registers
    const float* u0 = Ub + jown;
    float cu0 = u0[0 * H_DIM], cu1 = u0[1 * H_DIM];
    float cu2 = u0[2 * H_DIM], cu3 = u0[3 * H_DIM];
    float cu4 = u0[4 * H_DIM], cu5 = u0[5 * H_DIM];
    float cu6 = u0[6 * H_DIM], cu7 = u0[7 * H_DIM];
    const float* up = Ub + jown + CHK * H_DIM;   // chunk 1

    const bool wsel = (p < 4);
    const bool sel1 = (s1 != 0);
    const bool sel2 = (s2 != 0);

    __syncthreads();

#define RNN_STEP(HRD, HWR, UVAL)                                              \
    {                                                                         \
        const float4* hv = reinterpret_cast<const float4*>(HRD);              \
        vf2 a0 = vf2{0.f, 0.f}, b0 = vf2{0.f, 0.f};                           \
        vf2 a1 = vf2{0.f, 0.f}, b1 = vf2{0.f, 0.f};                           \
        vf2 a2 = vf2{0.f, 0.f}, b2 = vf2{0.f, 0.f};                           \
        vf2 a3 = vf2{0.f, 0.f}, b3 = vf2{0.f, 0.f};                           \
        _Pragma("unroll")                                                     \
        for (int m = 0; m < 8; ++m) {                                         \
            const float4 h4 = hv[8 * m + p];                                  \
            const vf2 hlo = vf2{h4.x, h4.y};                                  \
            const vf2 hhi = vf2{h4.z, h4.w};                                  \
            a0 = pkfma(w2[0][2 * m], hlo, a0);                                \
            b0 = pkfma(w2[0][2 * m + 1], hhi, b0);                            \
            a1 = pkfma(w2[1][2 * m], hlo, a1);                                \
            b1 = pkfma(w2[1][2 * m + 1], hhi, b1);                            \
            a2 = pkfma(w2[2][2 * m], hlo, a2);                                \
            b2 = pkfma(w2[2][2 * m + 1], hhi, b2);                            \
            a3 = pkfma(w2[3][2 * m], hlo, a3);                                \
            b3 = pkfma(w2[3][2 * m + 1], hhi, b3);                            \
        }                                                                     \
        const vf2 s0v = a0 + b0, s1v = a1 + b1;                               \
        const vf2 s2v = a2 + b2, s3v = a3 + b3;                               \
        const float d0 = s0v.x + s0v.y, d1 = s1v.x + s1v.y;                   \
        const float d2 = s2v.x + s2v.y, d3 = s3v.x + s3v.y;                   \
        /* xor1 (quad DPP) */                                                 \
        const float e0 = dpp_xadd<0xB1>(d0);                                  \
        const float e1 = dpp_xadd<0xB1>(d1);                                  \
        const float e2 = dpp_xadd<0xB1>(d2);                                  \
        const float e3 = dpp_xadd<0xB1>(d3);                                  \
        /* select by s1 = b0^b2 (invariant under ^2 and ^7) */                \
        const float c0 = sel1 ? e1 : e0;                                      \
        const float c1 = sel1 ? e3 : e2;                                      \
        /* xor2 (quad DPP) */                                                 \
        const float f0 = dpp_xadd<0x4E>(c0);                                  \
        const float f1 = dpp_xadd<0x4E>(c1);                                  \
        /* select by s2 = b0^b1 (invariant under ^7) */                       \
        const float gg = sel2 ? f1 : f0;                                      \
        /* xor7 via row_half_mirror DPP: full row sum, dup at p^7 */          \
        const float fr = dpp_xadd<0x141>(gg);                                 \
        const float hval = fast_tanh(fr + (UVAL));                            \
        if (wsel) { (HWR)[jown] = hval; *us = hval; }                         \
        us += H_DIM;                                                          \
        lds_barrier();                                                        \
    }

    for (int c = 0; c < NCHK; ++c) {
        // issue next-chunk u loads (consumed >= 8 steps later)
        const float nx0 = up[0 * H_DIM], nx1 = up[1 * H_DIM];
        const float nx2 = up[2 * H_DIM], nx3 = up[3 * H_DIM];
        const float nx4 = up[4 * H_DIM], nx5 = up[5 * H_DIM];
        const float nx6 = up[6 * H_DIM], nx7 = up[7 * H_DIM];

        RNN_STEP(hA, hB, cu0)
        RNN_STEP(hB, hA, cu1)
        RNN_STEP(hA, hB, cu2)
        RNN_STEP(hB, hA, cu3)
        RNN_STEP(hA, hB, cu4)
        RNN_STEP(hB, hA, cu5)
        RNN_STEP(hA, hB, cu6)
        RNN_STEP(hB, hA, cu7)

        cu0 = nx0; cu1 = nx1; cu2 = nx2; cu3 = nx3;
        cu4 = nx4; cu5 = nx5; cu6 = nx6; cu7 = nx7;
        if (c < NCHK - 2) up += CHK * H_DIM;   // stay on last chunk (no OOB)
    }
#undef RNN_STEP
}

// finalize: sigma[s][t] = |W_lin·h_t + b_lin|, log-lik reduction.
// H == U buffer (overwritten by rnn_main9 with h_t). grid (50,8).
__launch_bounds__(256, 4)
__global__ void finalize_kernel(const float* __restrict__ input_data,
                                const float* __restrict__ fe,
                                const float* __restrict__ W_lin,
                                const float* __restrict__ b_lin,
                                const float* __restrict__ H,
                                float* __restrict__ out)
{
    const int s    = blockIdx.x;
    const int tb   = blockIdx.y;   // 8 slices of 256 timesteps
    const int tid  = threadIdx.x;
    const int wave = tid >> 6;
    const int lane = tid & 63;

    const float4 wl =
        reinterpret_cast<const float4*>(W_lin + s * H_DIM)[lane];
    const float blin = b_lin[s];
    const float* Hb  = H + (size_t)s * T_CNT * H_DIM;
    const float* inb = input_data + (size_t)s * T_CNT * 65;
    const float* feb = fe + (size_t)s * T_CNT;
    float* sig_out   = out + 1 + (size_t)s * T_CNT;

    float ll = 0.f;
    for (int i = 0; i < 64; ++i) {
        const int t = tb * 256 + 4 * i + wave;
        const float4 h4 =
            reinterpret_cast<const float4*>(Hb + (size_t)t * H_DIM)[lane];
        float d = fma4(wl, h4, 0.f);
#pragma unroll
        for (int m = 1; m <= 32; m <<= 1) d += __shfl_xor(d, m);
        const float sigma = fabsf(d + blin);
        if (lane == 0) {
            sig_out[t] = sigma;
            const float diff = inb[(size_t)t * 65] - feb[t];
            ll -= (diff * diff) / (2.f * sigma * sigma);
        }
    }
    __shared__ float red[4];
    if (lane == 0) red[wave] = ll;
    __syncthreads();
    if (tid == 0) atomicAdd(out, (red[0] + red[1]) + (red[2] + red[3]));
}

// ---------------- fallback (no workspace): round-3 style, self-contained ----
__launch_bounds__(1024, 4)
__global__ void rnn_fallback_kernel(const float* __restrict__ input_data,
                                    const float* __restrict__ hidden,
                                    const float* __restrict__ fe,
                                    const float* __restrict__ W_ih,
                                    const float* __restrict__ W_hh,
                                    const float* __restrict__ b_ih,
                                    const float* __restrict__ b_hh,
                                    const float* __restrict__ W_lin,
                                    const float* __restrict__ b_lin,
                                    float* __restrict__ out)
{
    const int s    = blockIdx.x;
    const int tid  = threadIdx.x;
    const int j    = tid >> 2;
    const int q    = tid & 3;
    const int lane = tid & 63;
    const int wv   = tid >> 6;

    __shared__ float hbuf[2][H_DIM];
    __shared__ float zbuf[T_CNT];
    __shared__ float febuf[T_CNT];
    __shared__ float wlin_lds[H_DIM];
    __shared__ float wsum[2][16];
    __shared__ float xbuf[64][I_DIM];

    const float* in_base = input_data + (size_t)s * T_CNT * 65;
    const float* fe_base = fe + (size_t)s * T_CNT;

    for (int t = tid; t < T_CNT; t += 1024) {
        zbuf[t]  = in_base[(size_t)t * 65];
        febuf[t] = fe_base[t];
    }
    if (tid < H_DIM) {
        hbuf[1][tid]  = hidden[s * H_DIM + tid];
        wlin_lds[tid] = W_lin[s * H_DIM + tid];
    }

    float4 w[16];
    {
        const float4* wrow =
            reinterpret_cast<const float4*>(W_hh + ((size_t)s * H_DIM + j) * H_DIM);
#pragma unroll
        for (int m = 0; m < 16; ++m) w[m] = wrow[4 * m + q];
    }
    float4 wx[4];
    {
        const float4* wxrow =
            reinterpret_cast<const float4*>(W_ih + ((size_t)s * H_DIM + j) * I_DIM);
#pragma unroll
        for (int m = 0; m < 4; ++m) wx[m] = wxrow[4 * m + q];
    }
    const float badd = b_ih[s * H_DIM + j] + b_hh[s * H_DIM + j];
    const float blin = b_lin[s];
    float* sig_out = out + 1 + (size_t)s * T_CNT;

    float ll = 0.f, sv_prev = 0.f;
    __syncthreads();

    for (int c = 0; c < T_CNT / 64; ++c) {
        for (int idx = tid; idx < 64 * I_DIM; idx += 1024) {
            const int row = idx >> 6, col = idx & 63;
            xbuf[row][col] = in_base[(size_t)(c * 64 + row) * 65 + 1 + col];
        }
        __syncthreads();
        for (int tt = 0; tt < 64; ++tt) {
            const int t  = c * 64 + tt;
            const int rp = (t + 1) & 1;
            {
                float sv = sv_prev;
                sv += __shfl_xor(sv, 4);
                sv += __shfl_xor(sv, 8);
                sv += __shfl_xor(sv, 16);
                sv += __shfl_xor(sv, 32);
                if (lane == 0) wsum[(t - 1) & 1][wv] = sv;
            }
            if (tid == 0 && t >= 2) {
                const int tm = t - 2;
                const float* wp = wsum[tm & 1];
                float sg = (((wp[0] + wp[1]) + (wp[2] + wp[3])) +
                            ((wp[4] + wp[5]) + (wp[6] + wp[7]))) +
                           (((wp[8] + wp[9]) + (wp[10] + wp[11])) +
                            ((wp[12] + wp[13]) + (wp[14] + wp[15]))) + blin;
                const float sigma = fabsf(sg);
                sig_out[tm] = sigma;
                const float diff = zbuf[tm] - febuf[tm];
                ll -= (diff * diff) / (2.f * sigma * sigma);
            }
            const float4* hv = reinterpret_cast<const float4*>(&hbuf[rp][0]);
            float a0 = 0.f, a1 = 0.f, a2 = 0.f, a3 = 0.f;
#pragma unroll
            for (int m = 0; m < 16; m += 4) {
                a0 = fma4(w[m],     hv[4 * (m + 0) + q], a0);
                a1 = fma4(w[m + 1], hv[4 * (m + 1) + q], a1);
                a2 = fma4(w[m + 2], hv[4 * (m + 2) + q], a2);
                a3 = fma4(w[m + 3], hv[4 * (m + 3) + q], a3);
            }
            const float4* xv = reinterpret_cast<const float4*>(&xbuf[tt][0]);
#pragma unroll
            for (int m = 0; m < 4; ++m) a0 = fma4(wx[m], xv[4 * m + q], a0);

            float dot = (a0 + a1) + (a2 + a3);
            dot += __shfl_xor(dot, 1);
            dot += __shfl_xor(dot, 2);
            const float h = fast_tanh(dot + badd);
            if (q == 0) hbuf[t & 1][j] = h;
            sv_prev = h * wlin_lds[j];
            __syncthreads();
        }
        __syncthreads();
    }
    {
        float sv = sv_prev;
        sv += __shfl_xor(sv, 4);
        sv += __shfl_xor(sv, 8);
        sv += __shfl_xor(sv, 16);
        sv += __shfl_xor(sv, 32);
        if (lane == 0) wsum[(T_CNT - 1) & 1][wv] = sv;
    }
    __syncthreads();
    if (tid == 0) {
        for (int tm = T_CNT - 2; tm < T_CNT; ++tm) {
            const float* wp = wsum[tm & 1];
            float sg = (((wp[0] + wp[1]) + (wp[2] + wp[3])) +
                        ((wp[4] + wp[5]) + (wp[6] + wp[7]))) +
                       (((wp[8] + wp[9]) + (wp[10] + wp[11])) +
                        ((wp[12] + wp[13]) + (wp[14] + wp[15]))) + blin;
            const float sigma = fabsf(sg);
            sig_out[tm] = sigma;
            const float diff = zbuf[tm] - febuf[tm];
            ll -= (diff * diff) / (2.f * sigma * sigma);
        }
        atomicAdd(out, ll);
    }
}

extern "C" void kernel_launch(void* const* d_in, const int* in_sizes, int n_in,
                              void* d_out, int out_size, void* d_ws, size_t ws_size,
                              hipStream_t stream) {
    (void)in_sizes; (void)n_in; (void)out_size;
    const float* input_data = (const float*)d_in[0];
    const float* hidden     = (const float*)d_in[1];
    const float* fe         = (const float*)d_in[2];
    const float* W_ih       = (const float*)d_in[3];
    const float* W_hh       = (const float*)d_in[4];
    const float* b_ih       = (const float*)d_in[5];
    const float* b_hh       = (const float*)d_in[6];
    const float* W_lin      = (const float*)d_in[7];
    const float* b_lin      = (const float*)d_in[8];
    float* out = (float*)d_out;

    hipMemsetAsync(d_out, 0, sizeof(float), stream);

    const size_t u_bytes = (size_t)S_CNT * T_CNT * H_DIM * sizeof(float);

    if (ws_size >= u_bytes) {
        float* U = (float*)d_ws;
        precompute_v3<<<dim3(S_CNT, 32), 256, 0, stream>>>(
            input_data, W_ih, b_ih, b_hh, U);
        rnn_main9<<<dim3(S_CNT), dim3(512), 0, stream>>>(hidden, W_hh, U);
        finalize_kernel<<<dim3(S_CNT, 8), 256, 0, stream>>>(
            input_data, fe, W_lin, b_lin, U, out);
    } else {
        rnn_fallback_kernel<<<dim3(S_CNT), dim3(1024), 0, stream>>>(
            input_data, hidden, fe, W_ih, W_hh, b_ih, b_hh, W_lin, b_lin, out);
    }
}